// Round 1
// baseline (1726.210 us; speedup 1.0000x reference)
//
#include <hip/hip_runtime.h>
#include <math.h>

// Problem constants (B=8, T=1024, C=768, H=12, D=64)
#define BATCH 8
#define SEQ   1024
#define CH    768
#define NH    12
#define HD    64
#define HSZ   (BATCH * NH * SEQ * HD)   // 6291456 elements = B*T*C too

// ---------------------------------------------------------------------------
// GEMM: out[M,N] = A[M,K] @ W[K,N] + bias[N]
// MODE 0: plain row-major store
// MODE 1: scatter into q/k/v [B,H,T,D] buffers (out points at q; k,v follow
//         contiguously at +HSZ, +2*HSZ)
// 64x64 tile, BK=16, 256 threads, 4x4 micro-tile per thread. fp32.
// ---------------------------------------------------------------------------
template <int MODE>
__global__ __launch_bounds__(256) void gemm_kernel(
    const float* __restrict__ A, const float* __restrict__ W,
    const float* __restrict__ bias, float* __restrict__ out,
    int M, int N, int K)
{
    const int BM = 64, BN = 64, BK = 16;
    __shared__ float As[BK][BM + 4];   // +4 pad: keeps 16B alignment, breaks conflicts
    __shared__ float Bs[BK][BN + 4];

    const int tid = threadIdx.x;       // 0..255
    const int tx = tid & 15;           // n-dir
    const int ty = tid >> 4;           // m-dir
    const int m0 = blockIdx.y * BM;
    const int n0 = blockIdx.x * BN;

    float acc[4][4] = {};

    for (int k0 = 0; k0 < K; k0 += BK) {
        // A tile: 64 rows x 16 cols, store transposed As[k][m]
        #pragma unroll
        for (int i = 0; i < 4; i++) {
            int idx = i * 256 + tid;
            int r = idx >> 4;          // 0..63 (row in tile)
            int c = idx & 15;          // 0..15 (k in tile)
            As[c][r] = A[(size_t)(m0 + r) * K + k0 + c];
        }
        // B tile: 16 rows x 64 cols, natural layout Bs[k][n]
        #pragma unroll
        for (int i = 0; i < 4; i++) {
            int idx = i * 256 + tid;
            int r = idx >> 6;          // 0..15
            int c = idx & 63;          // 0..63
            Bs[r][c] = W[(size_t)(k0 + r) * N + n0 + c];
        }
        __syncthreads();

        #pragma unroll
        for (int kk = 0; kk < BK; kk++) {
            float a[4], b[4];
            #pragma unroll
            for (int i = 0; i < 4; i++) a[i] = As[kk][ty * 4 + i];
            #pragma unroll
            for (int j = 0; j < 4; j++) b[j] = Bs[kk][tx * 4 + j];
            #pragma unroll
            for (int i = 0; i < 4; i++)
                #pragma unroll
                for (int j = 0; j < 4; j++)
                    acc[i][j] += a[i] * b[j];
        }
        __syncthreads();
    }

    #pragma unroll
    for (int i = 0; i < 4; i++) {
        int m = m0 + ty * 4 + i;
        #pragma unroll
        for (int j = 0; j < 4; j++) {
            int n = n0 + tx * 4 + j;
            float v = acc[i][j] + bias[n];
            if (MODE == 0) {
                out[(size_t)m * N + n] = v;
            } else {
                // n in [0,3C): sel 0=q 1=k 2=v; rem -> (h,d); m -> (b,t)
                int sel = n / CH;
                int rem = n - sel * CH;
                int h = rem >> 6, d = rem & 63;
                int b = m >> 10, t = m & 1023;
                size_t dst = (size_t)sel * HSZ +
                             (((size_t)(b * NH + h)) * SEQ + t) * HD + d;
                out[dst] = v;
            }
        }
    }
}

// ---------------------------------------------------------------------------
// Flash-style causal attention, fp32.
// One wave (64 threads) per (b,h, 64-query tile). Thread t owns query row t
// of the tile: q[64] and o[64] in registers, online-softmax scalars m_i/l_i.
// K/V 64x64 tiles staged in LDS; dot-product reads are wave-broadcast.
// Causal: only key tiles kt <= qt; diagonal tile masked per-thread.
// ---------------------------------------------------------------------------
__global__ __launch_bounds__(64) void attn_kernel(
    const float* __restrict__ Q, const float* __restrict__ Km,
    const float* __restrict__ V, float* __restrict__ Y)
{
    __shared__ float Ksh[64 * 64];
    __shared__ float Vsh[64 * 64];

    const int tid = threadIdx.x;     // 0..63
    const int qt  = blockIdx.x;      // 0..15 query tile
    const int bh  = blockIdx.y;      // 0..95
    const int b = bh / NH;
    const int h = bh - b * NH;
    const size_t base = (size_t)bh * SEQ * HD;

    // Stage Q tile through LDS (coalesced), then copy own row to regs.
    for (int it = 0; it < 64; it++)
        Ksh[it * 64 + tid] = Q[base + (size_t)(qt * 64 + it) * HD + tid];
    __syncthreads();
    float q[64];
    #pragma unroll
    for (int d = 0; d < 64; d++) q[d] = Ksh[tid * 64 + d];
    __syncthreads();

    float o[64];
    #pragma unroll
    for (int d = 0; d < 64; d++) o[d] = 0.f;
    float m_i = -INFINITY, l_i = 0.f;
    const float scale = 0.125f;      // 1/sqrt(64)

    for (int kt = 0; kt <= qt; kt++) {
        for (int it = 0; it < 64; it++) {
            size_t src = base + (size_t)(kt * 64 + it) * HD + tid;
            Ksh[it * 64 + tid] = Km[src];
            Vsh[it * 64 + tid] = V[src];
        }
        __syncthreads();

        const int jmax = (kt == qt) ? (tid + 1) : 64;  // causal mask
        for (int j = 0; j < jmax; j++) {
            float s = 0.f;
            #pragma unroll
            for (int d = 0; d < 64; d++) s += q[d] * Ksh[j * 64 + d];
            s *= scale;
            float m_new = fmaxf(m_i, s);
            float alpha = __expf(m_i - m_new);   // 0 on first iter (-inf)
            float p     = __expf(s - m_new);
            l_i = l_i * alpha + p;
            #pragma unroll
            for (int d = 0; d < 64; d++)
                o[d] = o[d] * alpha + p * Vsh[j * 64 + d];
            m_i = m_new;
        }
        __syncthreads();
    }

    const float inv = 1.f / l_i;
    const int t = qt * 64 + tid;
    const size_t ybase = ((size_t)(b * SEQ + t)) * CH + h * HD;
    #pragma unroll
    for (int d = 0; d < 64; d++) Y[ybase + d] = o[d] * inv;
}

// ---------------------------------------------------------------------------
extern "C" void kernel_launch(void* const* d_in, const int* in_sizes, int n_in,
                              void* d_out, int out_size, void* d_ws, size_t ws_size,
                              hipStream_t stream)
{
    const float* x      = (const float*)d_in[0];  // [B,T,C]
    const float* w_attn = (const float*)d_in[1];  // [C,3C]
    const float* b_attn = (const float*)d_in[2];  // [3C]
    const float* w_proj = (const float*)d_in[3];  // [C,C]
    const float* b_proj = (const float*)d_in[4];  // [C]
    float* out = (float*)d_out;                   // [B,T,C]

    float* ws = (float*)d_ws;
    float* q  = ws;                // [B,H,T,D]
    // k = q + HSZ, v = q + 2*HSZ (scatter epilogue indexes off q)
    float* k  = ws + (size_t)HSZ;
    float* v  = ws + (size_t)2 * HSZ;
    float* y  = ws + (size_t)3 * HSZ;   // attention output [B,T,C]

    const int M = BATCH * SEQ;     // 8192

    // GEMM1: qkv = x @ w_attn + b_attn, scattered to q/k/v
    dim3 g1(3 * CH / 64, M / 64);  // (36, 128)
    gemm_kernel<1><<<g1, 256, 0, stream>>>(x, w_attn, b_attn, q, M, 3 * CH, CH);

    // Attention
    dim3 ga(SEQ / 64, BATCH * NH); // (16, 96)
    attn_kernel<<<ga, 64, 0, stream>>>(q, k, v, y);

    // GEMM2: out = y @ w_proj + b_proj
    dim3 g2(CH / 64, M / 64);      // (12, 128)
    gemm_kernel<0><<<g2, 256, 0, stream>>>(y, w_proj, b_proj, out, M, CH, CH);
}

// Round 2
// 695.906 us; speedup vs baseline: 2.4805x; 2.4805x over previous
//
#include <hip/hip_runtime.h>
#include <hip/hip_bf16.h>
#include <math.h>

// Problem constants (B=8, T=1024, C=768, H=12, D=64)
#define BATCH 8
#define SEQ   1024
#define CH    768
#define NH    12
#define HD    64
#define HSZ   (BATCH * NH * SEQ * HD)   // 6291456 elements = B*T*C

typedef __attribute__((ext_vector_type(8))) short short8;   // 8 bf16 = 4 VGPRs
typedef __attribute__((ext_vector_type(4))) float floatx4;  // MFMA C/D frag

// fp32 -> bf16 RNE
static __device__ inline short f2bf(float f) {
    union { float f; unsigned u; } x; x.f = f;
    unsigned r = (x.u + 0x7fffu + ((x.u >> 16) & 1u)) >> 16;
    return (short)r;
}

// ---------------------------------------------------------------------------
// GEMM: out[M,N] = A[M,K] @ W[K,N] + bias[N]   (fp32 compute)
// MODE 0: plain fp32 row-major store
// MODE 1: store bf16 into q/k/v buffers: q,k as [B,H,T,D]; v TRANSPOSED as
//         [B,H,D,T] (so attention can stage V^T with contiguous copies).
//         out points at q16; k16,v16 follow at +HSZ, +2*HSZ (bf16 elements).
// ---------------------------------------------------------------------------
template <int MODE>
__global__ __launch_bounds__(256) void gemm_kernel(
    const float* __restrict__ A, const float* __restrict__ W,
    const float* __restrict__ bias, void* __restrict__ outv,
    int M, int N, int K)
{
    const int BM = 64, BN = 64, BK = 16;
    __shared__ float As[BK][BM + 4];
    __shared__ float Bs[BK][BN + 4];

    const int tid = threadIdx.x;
    const int tx = tid & 15;           // n-dir
    const int ty = tid >> 4;           // m-dir
    const int m0 = blockIdx.y * BM;
    const int n0 = blockIdx.x * BN;

    float acc[4][4] = {};

    for (int k0 = 0; k0 < K; k0 += BK) {
        #pragma unroll
        for (int i = 0; i < 4; i++) {
            int idx = i * 256 + tid;
            int r = idx >> 4, c = idx & 15;
            As[c][r] = A[(size_t)(m0 + r) * K + k0 + c];
        }
        #pragma unroll
        for (int i = 0; i < 4; i++) {
            int idx = i * 256 + tid;
            int r = idx >> 6, c = idx & 63;
            Bs[r][c] = W[(size_t)(k0 + r) * N + n0 + c];
        }
        __syncthreads();

        #pragma unroll
        for (int kk = 0; kk < BK; kk++) {
            float a[4], b[4];
            #pragma unroll
            for (int i = 0; i < 4; i++) a[i] = As[kk][ty * 4 + i];
            #pragma unroll
            for (int j = 0; j < 4; j++) b[j] = Bs[kk][tx * 4 + j];
            #pragma unroll
            for (int i = 0; i < 4; i++)
                #pragma unroll
                for (int j = 0; j < 4; j++)
                    acc[i][j] += a[i] * b[j];
        }
        __syncthreads();
    }

    #pragma unroll
    for (int i = 0; i < 4; i++) {
        int m = m0 + ty * 4 + i;
        #pragma unroll
        for (int j = 0; j < 4; j++) {
            int n = n0 + tx * 4 + j;
            float v = acc[i][j] + bias[n];
            if (MODE == 0) {
                ((float*)outv)[(size_t)m * N + n] = v;
            } else {
                int sel = n / CH;
                int rem = n - sel * CH;
                int hh = rem >> 6, d = rem & 63;
                int bb = m >> 10, t = m & 1023;
                size_t dst;
                if (sel == 2)  // v transposed: [B,H,D,T]
                    dst = (size_t)2 * HSZ + (((size_t)(bb * NH + hh)) * HD + d) * SEQ + t;
                else
                    dst = (size_t)sel * HSZ + (((size_t)(bb * NH + hh)) * SEQ + t) * HD + d;
                ((short*)outv)[dst] = f2bf(v);
            }
        }
    }
}

// ---------------------------------------------------------------------------
// bf16 MFMA flash attention. Block = 256 threads (4 waves), one block per
// (b,h, 64-query tile). Wave w owns query rows w*16..w*16+15 of the tile.
// S strip (16x64) via 8x mfma_f32_16x16x32_bf16; strip softmax via 16-lane
// shfl_xor reductions (C/D layout: col=lane&15, row=quad*4+reg); P round-trips
// through LDS into A-layout (A[m=lane&15][k=quad*8+j]); PV via 8 more MFMAs.
// K staged [key][dim]; V staged transposed [dim][key]; rows padded +8 bf16
// (144B stride -> 2-way bank aliasing, free).
// ---------------------------------------------------------------------------
#define LDK 72   // padded row length (bf16 elements)

__global__ __launch_bounds__(256) void attn_kernel(
    const short* __restrict__ Qg, const short* __restrict__ Kg,
    const short* __restrict__ Vg, float* __restrict__ Y)
{
    __shared__ __align__(16) short Ksh[64 * LDK];
    __shared__ __align__(16) short Vsh[64 * LDK];      // [dim][key]
    __shared__ __align__(16) short Psh[4][16 * LDK];   // per-wave P strip

    const int tid  = threadIdx.x;
    const int wave = tid >> 6;
    const int lane = tid & 63;
    const int col  = lane & 15;
    const int quad = lane >> 4;
    const int qt = blockIdx.x;     // 0..15
    const int bh = blockIdx.y;     // 0..95
    const int b = bh / NH, h = bh - b * NH;

    const size_t kqbase = (size_t)bh * SEQ * HD;   // q,k: [bh][t][d]
    const size_t vbase  = (size_t)bh * HD * SEQ;   // v:   [bh][d][t]

    // Q A-fragments direct from global: m = qt*64 + wave*16 + col, k = s*32+quad*8+j
    short8 aq[2];
    {
        const short* qp = Qg + kqbase + (size_t)(qt * 64 + wave * 16 + col) * HD + quad * 8;
        aq[0] = *(const short8*)(qp);
        aq[1] = *(const short8*)(qp + 32);
    }

    floatx4 acc_o[4] = {{0.f,0.f,0.f,0.f},{0.f,0.f,0.f,0.f},
                        {0.f,0.f,0.f,0.f},{0.f,0.f,0.f,0.f}};
    float m_i[4], l_i[4];
    #pragma unroll
    for (int r = 0; r < 4; r++) { m_i[r] = -INFINITY; l_i[r] = 0.f; }

    const int qrow0 = wave * 16 + quad * 4;   // local query row of reg 0

    for (int kt = 0; kt <= qt; kt++) {
        __syncthreads();   // protect Ksh/Vsh from previous iteration's readers
        {
            const short* ksrc = Kg + kqbase + (size_t)kt * 64 * HD;
            const short* vsrc = Vg + vbase + kt * 64;
            #pragma unroll
            for (int i = 0; i < 2; i++) {
                int idx = (i * 256 + tid) * 8;   // 0..4088
                int row = idx >> 6;              // key (K) / dim (V)
                int off = idx & 63;
                *(short8*)&Ksh[row * LDK + off] = *(const short8*)&ksrc[idx];
                *(short8*)&Vsh[row * LDK + off] = *(const short8*)&vsrc[(size_t)row * SEQ + off];
            }
        }
        __syncthreads();

        // --- S = Q K^T strip ---
        floatx4 sacc[4] = {{0.f,0.f,0.f,0.f},{0.f,0.f,0.f,0.f},
                           {0.f,0.f,0.f,0.f},{0.f,0.f,0.f,0.f}};
        #pragma unroll
        for (int s = 0; s < 2; s++)
            #pragma unroll
            for (int nt = 0; nt < 4; nt++) {
                short8 bk = *(short8*)&Ksh[(nt * 16 + col) * LDK + s * 32 + quad * 8];
                sacc[nt] = __builtin_amdgcn_mfma_f32_16x16x32_bf16(aq[s], bk, sacc[nt], 0, 0, 0);
            }

        // --- scale, mask, online softmax (rows quad*4+r, shared by 16-lane group) ---
        float p[4][4];
        #pragma unroll
        for (int r = 0; r < 4; r++) {
            float mv = -INFINITY;
            #pragma unroll
            for (int nt = 0; nt < 4; nt++) {
                float s = sacc[nt][r] * 0.125f;
                if (kt == qt && (nt * 16 + col) > (qrow0 + r)) s = -INFINITY;
                p[nt][r] = s;
                mv = fmaxf(mv, s);
            }
            #pragma unroll
            for (int off = 1; off < 16; off <<= 1)
                mv = fmaxf(mv, __shfl_xor(mv, off));
            float mnew = fmaxf(m_i[r], mv);
            float alpha = __expf(m_i[r] - mnew);
            float rsum = 0.f;
            #pragma unroll
            for (int nt = 0; nt < 4; nt++) {
                float e = __expf(p[nt][r] - mnew);
                p[nt][r] = e;
                rsum += e;
            }
            #pragma unroll
            for (int off = 1; off < 16; off <<= 1)
                rsum += __shfl_xor(rsum, off);
            l_i[r] = l_i[r] * alpha + rsum;
            m_i[r] = mnew;
            #pragma unroll
            for (int nt = 0; nt < 4; nt++) acc_o[nt][r] *= alpha;
        }

        // --- P -> LDS (C/D layout in, A layout out) ---
        short* pw = Psh[wave];
        #pragma unroll
        for (int r = 0; r < 4; r++)
            #pragma unroll
            for (int nt = 0; nt < 4; nt++)
                pw[(quad * 4 + r) * LDK + nt * 16 + col] = f2bf(p[nt][r]);
        __syncthreads();

        short8 ap[2];
        ap[0] = *(short8*)&pw[col * LDK + quad * 8];
        ap[1] = *(short8*)&pw[col * LDK + 32 + quad * 8];

        // --- O += P V ---
        #pragma unroll
        for (int s = 0; s < 2; s++)
            #pragma unroll
            for (int nt = 0; nt < 4; nt++) {
                short8 bv = *(short8*)&Vsh[(nt * 16 + col) * LDK + s * 32 + quad * 8];
                acc_o[nt] = __builtin_amdgcn_mfma_f32_16x16x32_bf16(ap[s], bv, acc_o[nt], 0, 0, 0);
            }
    }

    // --- epilogue: normalize, write y[B,T,C] fp32 ---
    #pragma unroll
    for (int r = 0; r < 4; r++) {
        float inv = 1.f / l_i[r];
        int t = qt * 64 + qrow0 + r;
        size_t ybase = ((size_t)(b * SEQ + t)) * CH + h * HD;
        #pragma unroll
        for (int nt = 0; nt < 4; nt++)
            Y[ybase + nt * 16 + col] = acc_o[nt][r] * inv;
    }
}

// ---------------------------------------------------------------------------
extern "C" void kernel_launch(void* const* d_in, const int* in_sizes, int n_in,
                              void* d_out, int out_size, void* d_ws, size_t ws_size,
                              hipStream_t stream)
{
    const float* x      = (const float*)d_in[0];
    const float* w_attn = (const float*)d_in[1];
    const float* b_attn = (const float*)d_in[2];
    const float* w_proj = (const float*)d_in[3];
    const float* b_proj = (const float*)d_in[4];
    float* out = (float*)d_out;

    short* qkv16 = (short*)d_ws;                       // q,k,v bf16 (3*HSZ shorts)
    float* y     = (float*)((char*)d_ws + (size_t)3 * HSZ * sizeof(short));  // [B,T,C] fp32

    const int M = BATCH * SEQ;   // 8192

    // GEMM1: qkv = x @ w_attn + b_attn -> bf16 q/k/v (v transposed)
    dim3 g1(3 * CH / 64, M / 64);
    gemm_kernel<1><<<g1, 256, 0, stream>>>(x, w_attn, b_attn, qkv16, M, 3 * CH, CH);

    // Flash attention
    dim3 ga(SEQ / 64, BATCH * NH);
    attn_kernel<<<ga, 256, 0, stream>>>(qkv16, qkv16 + (size_t)HSZ,
                                        qkv16 + (size_t)2 * HSZ, y);

    // GEMM2: out = y @ w_proj + b_proj (fp32)
    dim3 g2(CH / 64, M / 64);
    gemm_kernel<0><<<g2, 256, 0, stream>>>(y, w_proj, b_proj, out, M, CH, CH);
}

// Round 3
// 281.404 us; speedup vs baseline: 6.1343x; 2.4730x over previous
//
#include <hip/hip_runtime.h>
#include <hip/hip_bf16.h>
#include <math.h>

// Problem constants (B=8, T=1024, C=768, H=12, D=64)
#define BATCH 8
#define SEQ   1024
#define CH    768
#define NH    12
#define HD    64
#define HSZ   (BATCH * NH * SEQ * HD)   // 6291456 elements = B*T*C

typedef __attribute__((ext_vector_type(8))) short short8;   // 8 bf16 = 4 VGPRs
typedef __attribute__((ext_vector_type(4))) short short4v;
typedef __attribute__((ext_vector_type(4))) float floatx4;  // MFMA C/D frag

// fp32 -> bf16 RNE
static __device__ inline short f2bf(float f) {
    union { float f; unsigned u; } x; x.f = f;
    unsigned r = (x.u + 0x7fffu + ((x.u >> 16) & 1u)) >> 16;
    return (short)r;
}

// async global->LDS, 16B per lane; LDS dest must be wave-uniform base + lane*16
#define GLOAD_LDS16(g, l)                                                     \
    __builtin_amdgcn_global_load_lds(                                         \
        (const __attribute__((address_space(1))) void*)(g),                   \
        (__attribute__((address_space(3))) void*)(l), 16, 0, 0)

// ---------------------------------------------------------------------------
// Prep: fp32 -> bf16 cast (x), and fp32 [K,N] -> bf16 [N,K] transpose-cast (W)
// ---------------------------------------------------------------------------
__global__ __launch_bounds__(256) void cast_kernel(
    const float* __restrict__ in, short* __restrict__ out, int n)
{
    int i = (blockIdx.x * 256 + threadIdx.x) * 4;
    if (i < n) {
        float4 v = *(const float4*)(in + i);
        short4v o = { f2bf(v.x), f2bf(v.y), f2bf(v.z), f2bf(v.w) };
        *(short4v*)(out + i) = o;
    }
}

__global__ __launch_bounds__(256) void transpose_cast_kernel(
    const float* __restrict__ w, short* __restrict__ wt, int K, int N)
{
    __shared__ float tile[32][33];
    const int tx = threadIdx.x;        // 0..31
    const int ty = threadIdx.y;        // 0..7
    const int n0 = blockIdx.x * 32, k0 = blockIdx.y * 32;
    #pragma unroll
    for (int i = 0; i < 4; i++)
        tile[ty + i * 8][tx] = w[(size_t)(k0 + ty + i * 8) * N + n0 + tx];
    __syncthreads();
    #pragma unroll
    for (int i = 0; i < 4; i++)
        wt[(size_t)(n0 + ty + i * 8) * K + k0 + tx] = f2bf(tile[tx][ty + i * 8]);
}

// ---------------------------------------------------------------------------
// m97-style bf16 MFMA GEMM:  C[M,N] = A[M,K] @ Bt[N,K]^T + bias[N]
// 128x128 tile, BK=32, 256 threads = 4 waves in 2x2; each wave does 64x64 via
// 4x4 grid of mfma_f32_16x16x32_bf16. global_load_lds width=16 staging into
// unpadded [row][32] LDS (row = 64 B).
// MODE 0: fp32 row-major store (out = proj output)
// MODE 1: bf16 scatter to q/k/v: q,k [B,H,T,D]; v transposed [B,H,D,T].
//         outv points at q; k,v follow at +HSZ, +2*HSZ (bf16 elements).
// ---------------------------------------------------------------------------
template <int MODE>
__global__ __launch_bounds__(256) void gemm_bt_kernel(
    const short* __restrict__ A, const short* __restrict__ Bt,
    const float* __restrict__ bias, void* __restrict__ outv,
    int M, int N, int K)
{
    __shared__ __align__(16) short As[128 * 32];
    __shared__ __align__(16) short Bs[128 * 32];

    const int tid  = threadIdx.x;
    const int lane = tid & 63;
    const int col  = lane & 15;
    const int quad = lane >> 4;
    const int wave = tid >> 6;
    const int wm = wave & 1, wn = wave >> 1;
    const int m0 = blockIdx.y * 128, n0 = blockIdx.x * 128;

    // Staging: tile is 128 rows x 64 B. Each thread moves 2x16 B per operand.
    const int off0 = tid * 16;          // byte 0..4080
    const int off1 = 4096 + tid * 16;   // byte 4096..8176
    const int row0 = off0 >> 6, in0 = (off0 & 63) >> 1;
    const int row1 = off1 >> 6, in1 = (off1 & 63) >> 1;
    const short* ag0 = A  + (size_t)(m0 + row0) * K + in0;
    const short* ag1 = A  + (size_t)(m0 + row1) * K + in1;
    const short* bg0 = Bt + (size_t)(n0 + row0) * K + in0;
    const short* bg1 = Bt + (size_t)(n0 + row1) * K + in1;
    short* al0 = As + (off0 >> 1);
    short* al1 = As + (off1 >> 1);
    short* bl0 = Bs + (off0 >> 1);
    short* bl1 = Bs + (off1 >> 1);

    floatx4 acc[4][4];
    #pragma unroll
    for (int i = 0; i < 4; i++)
        #pragma unroll
        for (int j = 0; j < 4; j++)
            acc[i][j] = (floatx4){0.f, 0.f, 0.f, 0.f};

    for (int k0 = 0; k0 < K; k0 += 32) {
        __syncthreads();                 // protect LDS from prior iter's readers
        GLOAD_LDS16(ag0 + k0, al0);
        GLOAD_LDS16(ag1 + k0, al1);
        GLOAD_LDS16(bg0 + k0, bl0);
        GLOAD_LDS16(bg1 + k0, bl1);
        __syncthreads();                 // drains vmcnt (compiler-inserted)

        short8 af[4], bf[4];
        #pragma unroll
        for (int mt = 0; mt < 4; mt++)
            af[mt] = *(short8*)&As[(wm * 64 + mt * 16 + col) * 32 + quad * 8];
        #pragma unroll
        for (int nt = 0; nt < 4; nt++)
            bf[nt] = *(short8*)&Bs[(wn * 64 + nt * 16 + col) * 32 + quad * 8];
        #pragma unroll
        for (int mt = 0; mt < 4; mt++)
            #pragma unroll
            for (int nt = 0; nt < 4; nt++)
                acc[mt][nt] = __builtin_amdgcn_mfma_f32_16x16x32_bf16(
                    af[mt], bf[nt], acc[mt][nt], 0, 0, 0);
    }

    // Epilogue. C/D layout: row = quad*4 + r, col = col (verified m89/m91).
    #pragma unroll
    for (int mt = 0; mt < 4; mt++) {
        #pragma unroll
        for (int r = 0; r < 4; r++) {
            const int m = m0 + wm * 64 + mt * 16 + quad * 4 + r;
            const int bb = m >> 10, t = m & 1023;
            #pragma unroll
            for (int nt = 0; nt < 4; nt++) {
                const int n = n0 + wn * 64 + nt * 16 + col;
                const float v = acc[mt][nt][r] + bias[n];
                if (MODE == 0) {
                    ((float*)outv)[(size_t)m * N + n] = v;
                } else {
                    const int sel = n / CH;
                    const int rem = n - sel * CH;
                    const int hh = rem >> 6, d = rem & 63;
                    size_t dst;
                    if (sel == 2)   // v transposed: [B,H,D,T]
                        dst = (size_t)2 * HSZ + (((size_t)(bb * NH + hh)) * HD + d) * SEQ + t;
                    else
                        dst = (size_t)sel * HSZ + (((size_t)(bb * NH + hh)) * SEQ + t) * HD + d;
                    ((short*)outv)[dst] = f2bf(v);
                }
            }
        }
    }
}

// ---------------------------------------------------------------------------
// bf16 MFMA flash attention (unchanged from round 2 except bf16 Y store).
// Block = 256 threads (4 waves), one block per (b,h, 64-query tile).
// ---------------------------------------------------------------------------
#define LDK 72   // padded row length (bf16 elements)

__global__ __launch_bounds__(256) void attn_kernel(
    const short* __restrict__ Qg, const short* __restrict__ Kg,
    const short* __restrict__ Vg, short* __restrict__ Y)
{
    __shared__ __align__(16) short Ksh[64 * LDK];
    __shared__ __align__(16) short Vsh[64 * LDK];      // [dim][key]
    __shared__ __align__(16) short Psh[4][16 * LDK];   // per-wave P strip

    const int tid  = threadIdx.x;
    const int wave = tid >> 6;
    const int lane = tid & 63;
    const int col  = lane & 15;
    const int quad = lane >> 4;
    const int qt = blockIdx.x;     // 0..15
    const int bh = blockIdx.y;     // 0..95
    const int b = bh / NH, h = bh - b * NH;

    const size_t kqbase = (size_t)bh * SEQ * HD;   // q,k: [bh][t][d]
    const size_t vbase  = (size_t)bh * HD * SEQ;   // v:   [bh][d][t]

    short8 aq[2];
    {
        const short* qp = Qg + kqbase + (size_t)(qt * 64 + wave * 16 + col) * HD + quad * 8;
        aq[0] = *(const short8*)(qp);
        aq[1] = *(const short8*)(qp + 32);
    }

    floatx4 acc_o[4];
    #pragma unroll
    for (int i = 0; i < 4; i++) acc_o[i] = (floatx4){0.f, 0.f, 0.f, 0.f};
    float m_i[4], l_i[4];
    #pragma unroll
    for (int r = 0; r < 4; r++) { m_i[r] = -INFINITY; l_i[r] = 0.f; }

    const int qrow0 = wave * 16 + quad * 4;

    for (int kt = 0; kt <= qt; kt++) {
        __syncthreads();
        {
            const short* ksrc = Kg + kqbase + (size_t)kt * 64 * HD;
            const short* vsrc = Vg + vbase + kt * 64;
            #pragma unroll
            for (int i = 0; i < 2; i++) {
                int idx = (i * 256 + tid) * 8;
                int row = idx >> 6;
                int off = idx & 63;
                *(short8*)&Ksh[row * LDK + off] = *(const short8*)&ksrc[idx];
                *(short8*)&Vsh[row * LDK + off] = *(const short8*)&vsrc[(size_t)row * SEQ + off];
            }
        }
        __syncthreads();

        floatx4 sacc[4];
        #pragma unroll
        for (int i = 0; i < 4; i++) sacc[i] = (floatx4){0.f, 0.f, 0.f, 0.f};
        #pragma unroll
        for (int s = 0; s < 2; s++)
            #pragma unroll
            for (int nt = 0; nt < 4; nt++) {
                short8 bk = *(short8*)&Ksh[(nt * 16 + col) * LDK + s * 32 + quad * 8];
                sacc[nt] = __builtin_amdgcn_mfma_f32_16x16x32_bf16(aq[s], bk, sacc[nt], 0, 0, 0);
            }

        float p[4][4];
        #pragma unroll
        for (int r = 0; r < 4; r++) {
            float mv = -INFINITY;
            #pragma unroll
            for (int nt = 0; nt < 4; nt++) {
                float s = sacc[nt][r] * 0.125f;
                if (kt == qt && (nt * 16 + col) > (qrow0 + r)) s = -INFINITY;
                p[nt][r] = s;
                mv = fmaxf(mv, s);
            }
            #pragma unroll
            for (int off = 1; off < 16; off <<= 1)
                mv = fmaxf(mv, __shfl_xor(mv, off));
            float mnew = fmaxf(m_i[r], mv);
            float alpha = __expf(m_i[r] - mnew);
            float rsum = 0.f;
            #pragma unroll
            for (int nt = 0; nt < 4; nt++) {
                float e = __expf(p[nt][r] - mnew);
                p[nt][r] = e;
                rsum += e;
            }
            #pragma unroll
            for (int off = 1; off < 16; off <<= 1)
                rsum += __shfl_xor(rsum, off);
            l_i[r] = l_i[r] * alpha + rsum;
            m_i[r] = mnew;
            #pragma unroll
            for (int nt = 0; nt < 4; nt++) acc_o[nt][r] *= alpha;
        }

        short* pw = Psh[wave];
        #pragma unroll
        for (int r = 0; r < 4; r++)
            #pragma unroll
            for (int nt = 0; nt < 4; nt++)
                pw[(quad * 4 + r) * LDK + nt * 16 + col] = f2bf(p[nt][r]);
        __syncthreads();

        short8 ap[2];
        ap[0] = *(short8*)&pw[col * LDK + quad * 8];
        ap[1] = *(short8*)&pw[col * LDK + 32 + quad * 8];

        #pragma unroll
        for (int s = 0; s < 2; s++)
            #pragma unroll
            for (int nt = 0; nt < 4; nt++) {
                short8 bv = *(short8*)&Vsh[(nt * 16 + col) * LDK + s * 32 + quad * 8];
                acc_o[nt] = __builtin_amdgcn_mfma_f32_16x16x32_bf16(ap[s], bv, acc_o[nt], 0, 0, 0);
            }
    }

    // epilogue: normalize, write y[B,T,C] bf16 (feeds GEMM2 directly)
    #pragma unroll
    for (int r = 0; r < 4; r++) {
        float inv = 1.f / l_i[r];
        int t = qt * 64 + qrow0 + r;
        size_t ybase = ((size_t)(b * SEQ + t)) * CH + h * HD;
        #pragma unroll
        for (int nt = 0; nt < 4; nt++)
            Y[ybase + nt * 16 + col] = f2bf(acc_o[nt][r] * inv);
    }
}

// ---------------------------------------------------------------------------
extern "C" void kernel_launch(void* const* d_in, const int* in_sizes, int n_in,
                              void* d_out, int out_size, void* d_ws, size_t ws_size,
                              hipStream_t stream)
{
    const float* x      = (const float*)d_in[0];  // [B,T,C]
    const float* w_attn = (const float*)d_in[1];  // [C,3C]
    const float* b_attn = (const float*)d_in[2];  // [3C]
    const float* w_proj = (const float*)d_in[3];  // [C,C]
    const float* b_proj = (const float*)d_in[4];  // [C]
    float* out = (float*)d_out;                   // [B,T,C] fp32

    // workspace layout (bf16 shorts unless noted)
    short* qkv16 = (short*)d_ws;                          // 3*HSZ
    short* y16   = qkv16 + (size_t)3 * HSZ;               // HSZ   [B,T,C]
    short* xb    = y16   + (size_t)HSZ;                   // HSZ   [B*T, C]
    short* wta   = xb    + (size_t)HSZ;                   // [3C, C] = w_attn^T
    short* wtp   = wta   + (size_t)3 * CH * CH;           // [C, C]  = w_proj^T

    const int M = BATCH * SEQ;   // 8192

    // Prep: cast x, transpose-cast weights
    cast_kernel<<<(M * CH / 4 + 255) / 256, 256, 0, stream>>>(x, xb, M * CH);
    {
        dim3 blk(32, 8);
        dim3 g_wa(3 * CH / 32, CH / 32);   // N=2304, K=768
        transpose_cast_kernel<<<g_wa, blk, 0, stream>>>(w_attn, wta, CH, 3 * CH);
        dim3 g_wp(CH / 32, CH / 32);
        transpose_cast_kernel<<<g_wp, blk, 0, stream>>>(w_proj, wtp, CH, CH);
    }

    // GEMM1: qkv = x @ w_attn + b_attn -> bf16 q/k/v (v transposed)
    dim3 g1(3 * CH / 128, M / 128);    // (18, 64)
    gemm_bt_kernel<1><<<g1, 256, 0, stream>>>(xb, wta, b_attn, qkv16, M, 3 * CH, CH);

    // Flash attention -> y16 bf16 [B,T,C]
    dim3 ga(SEQ / 64, BATCH * NH);     // (16, 96)
    attn_kernel<<<ga, 256, 0, stream>>>(qkv16, qkv16 + (size_t)HSZ,
                                        qkv16 + (size_t)2 * HSZ, y16);

    // GEMM2: out = y @ w_proj + b_proj (fp32 out)
    dim3 g2(CH / 128, M / 128);        // (6, 64)
    gemm_bt_kernel<0><<<g2, 256, 0, stream>>>(y16, wtp, b_proj, out, M, CH, CH);
}

// Round 4
// 228.781 us; speedup vs baseline: 7.5453x; 1.2300x over previous
//
#include <hip/hip_runtime.h>
#include <hip/hip_bf16.h>
#include <math.h>

// Problem constants (B=8, T=1024, C=768, H=12, D=64)
#define BATCH 8
#define SEQ   1024
#define CH    768
#define NH    12
#define HD    64
#define HSZ   (BATCH * NH * SEQ * HD)   // 6291456 elements = B*T*C

typedef __attribute__((ext_vector_type(8))) short short8;   // 8 bf16 = 4 VGPRs
typedef __attribute__((ext_vector_type(4))) short short4v;
typedef __attribute__((ext_vector_type(4))) float floatx4;  // MFMA C/D frag

// fp32 -> bf16 RNE
static __device__ inline short f2bf(float f) {
    union { float f; unsigned u; } x; x.f = f;
    unsigned r = (x.u + 0x7fffu + ((x.u >> 16) & 1u)) >> 16;
    return (short)r;
}

// async global->LDS, 16B per lane; LDS dest must be wave-uniform base + lane*16
#define GLOAD_LDS16(g, l)                                                     \
    __builtin_amdgcn_global_load_lds(                                         \
        (const __attribute__((address_space(1))) void*)(g),                   \
        (__attribute__((address_space(3))) void*)(l), 16, 0, 0)

// ---------------------------------------------------------------------------
// Fused prep (one launch): cast x fp32->bf16; transpose-cast w_attn and w_proj
// to bf16 [N,K]. Block role decoded from blockIdx.x.
// ---------------------------------------------------------------------------
#define NCAST (BATCH * SEQ * CH / 1024)          // 6144 blocks, 1024 elems each
#define NTA   ((3 * CH / 32) * (CH / 32))        // 1728 tiles for w_attn
#define NTP   ((CH / 32) * (CH / 32))            // 576 tiles for w_proj

__device__ __forceinline__ void transpose_tile(
    const float* __restrict__ w, short* __restrict__ wt, int K, int N,
    int bx, int by, int tid, float (*tile)[33])
{
    const int tx = tid & 31, ty = tid >> 5;      // 32 x 8
    const int n0 = bx * 32, k0 = by * 32;
    #pragma unroll
    for (int i = 0; i < 4; i++)
        tile[ty + i * 8][tx] = w[(size_t)(k0 + ty + i * 8) * N + n0 + tx];
    __syncthreads();
    #pragma unroll
    for (int i = 0; i < 4; i++)
        wt[(size_t)(n0 + ty + i * 8) * K + k0 + tx] = f2bf(tile[tx][ty + i * 8]);
}

__global__ __launch_bounds__(256) void prep_kernel(
    const float* __restrict__ x, short* __restrict__ xb,
    const float* __restrict__ wa, short* __restrict__ wta,
    const float* __restrict__ wp, short* __restrict__ wtp)
{
    __shared__ float tile[32][33];
    const int bid = blockIdx.x, tid = threadIdx.x;
    if (bid < NCAST) {
        int i = (bid * 256 + tid) * 4;
        float4 v = *(const float4*)(x + i);
        short4v o = { f2bf(v.x), f2bf(v.y), f2bf(v.z), f2bf(v.w) };
        *(short4v*)(xb + i) = o;
    } else if (bid < NCAST + NTA) {
        int t = bid - NCAST;
        transpose_tile(wa, wta, CH, 3 * CH, t % (3 * CH / 32), t / (3 * CH / 32), tid, tile);
    } else {
        int t = bid - NCAST - NTA;
        transpose_tile(wp, wtp, CH, CH, t % (CH / 32), t / (CH / 32), tid, tile);
    }
}

// ---------------------------------------------------------------------------
// m97-style bf16 MFMA GEMM:  C[M,N] = A[M,K] @ Bt[N,K]^T + bias[N]
// 128x128 tile, BK=32, 256 threads = 4 waves in 2x2; each wave does 64x64 via
// 4x4 grid of mfma_f32_16x16x32_bf16. global_load_lds width=16 staging.
// MODE 0: fp32 row-major store; MODE 1: bf16 scatter to q/k/v (v transposed).
// ---------------------------------------------------------------------------
template <int MODE>
__global__ __launch_bounds__(256) void gemm_bt_kernel(
    const short* __restrict__ A, const short* __restrict__ Bt,
    const float* __restrict__ bias, void* __restrict__ outv,
    int M, int N, int K)
{
    __shared__ __align__(16) short As[128 * 32];
    __shared__ __align__(16) short Bs[128 * 32];

    const int tid  = threadIdx.x;
    const int lane = tid & 63;
    const int col  = lane & 15;
    const int quad = lane >> 4;
    const int wave = tid >> 6;
    const int wm = wave & 1, wn = wave >> 1;
    const int m0 = blockIdx.y * 128, n0 = blockIdx.x * 128;

    const int off0 = tid * 16;          // byte 0..4080
    const int off1 = 4096 + tid * 16;   // byte 4096..8176
    const int row0 = off0 >> 6, in0 = (off0 & 63) >> 1;
    const int row1 = off1 >> 6, in1 = (off1 & 63) >> 1;
    const short* ag0 = A  + (size_t)(m0 + row0) * K + in0;
    const short* ag1 = A  + (size_t)(m0 + row1) * K + in1;
    const short* bg0 = Bt + (size_t)(n0 + row0) * K + in0;
    const short* bg1 = Bt + (size_t)(n0 + row1) * K + in1;
    short* al0 = As + (off0 >> 1);
    short* al1 = As + (off1 >> 1);
    short* bl0 = Bs + (off0 >> 1);
    short* bl1 = Bs + (off1 >> 1);

    floatx4 acc[4][4];
    #pragma unroll
    for (int i = 0; i < 4; i++)
        #pragma unroll
        for (int j = 0; j < 4; j++)
            acc[i][j] = (floatx4){0.f, 0.f, 0.f, 0.f};

    for (int k0 = 0; k0 < K; k0 += 32) {
        __syncthreads();
        GLOAD_LDS16(ag0 + k0, al0);
        GLOAD_LDS16(ag1 + k0, al1);
        GLOAD_LDS16(bg0 + k0, bl0);
        GLOAD_LDS16(bg1 + k0, bl1);
        __syncthreads();

        short8 af[4], bf[4];
        #pragma unroll
        for (int mt = 0; mt < 4; mt++)
            af[mt] = *(short8*)&As[(wm * 64 + mt * 16 + col) * 32 + quad * 8];
        #pragma unroll
        for (int nt = 0; nt < 4; nt++)
            bf[nt] = *(short8*)&Bs[(wn * 64 + nt * 16 + col) * 32 + quad * 8];
        #pragma unroll
        for (int mt = 0; mt < 4; mt++)
            #pragma unroll
            for (int nt = 0; nt < 4; nt++)
                acc[mt][nt] = __builtin_amdgcn_mfma_f32_16x16x32_bf16(
                    af[mt], bf[nt], acc[mt][nt], 0, 0, 0);
    }

    #pragma unroll
    for (int mt = 0; mt < 4; mt++) {
        #pragma unroll
        for (int r = 0; r < 4; r++) {
            const int m = m0 + wm * 64 + mt * 16 + quad * 4 + r;
            const int bb = m >> 10, t = m & 1023;
            #pragma unroll
            for (int nt = 0; nt < 4; nt++) {
                const int n = n0 + wn * 64 + nt * 16 + col;
                const float v = acc[mt][nt][r] + bias[n];
                if (MODE == 0) {
                    ((float*)outv)[(size_t)m * N + n] = v;
                } else {
                    const int sel = n / CH;
                    const int rem = n - sel * CH;
                    const int hh = rem >> 6, d = rem & 63;
                    size_t dst;
                    if (sel == 2)   // v transposed: [B,H,D,T]
                        dst = (size_t)2 * HSZ + (((size_t)(bb * NH + hh)) * HD + d) * SEQ + t;
                    else
                        dst = (size_t)sel * HSZ + (((size_t)(bb * NH + hh)) * SEQ + t) * HD + d;
                    ((short*)outv)[dst] = f2bf(v);
                }
            }
        }
    }
}

// ---------------------------------------------------------------------------
// bf16 MFMA flash attention, round-4 structure:
//  - software-pipelined K/V staging (prefetch kt+1 into regs during compute)
//  - 2 barriers per k-tile (P round-trip is wave-private: no barrier)
//  - diagonal tile peeled (mask-free main loop), exp2-domain softmax
//  - heavy-first dispatch: qt = 15 - blockIdx.y, bh = blockIdx.x
// ---------------------------------------------------------------------------
#define LDK 72   // padded row length (bf16) -> 144 B stride, 2-way bank alias (free)

template <bool DIAG>
__device__ __forceinline__ void attn_step(
    const short* __restrict__ Ksh, const short* __restrict__ Vsh,
    short* __restrict__ pw, const short8* aq, floatx4* acc_o,
    float* m_i, float* l_i, int col, int quad, int qrow0)
{
    // --- S = Q K^T strip (16 q-rows x 64 keys) ---
    floatx4 sacc[4];
    #pragma unroll
    for (int i = 0; i < 4; i++) sacc[i] = (floatx4){0.f, 0.f, 0.f, 0.f};
    #pragma unroll
    for (int s = 0; s < 2; s++)
        #pragma unroll
        for (int nt = 0; nt < 4; nt++) {
            short8 bk = *(const short8*)&Ksh[(nt * 16 + col) * LDK + s * 32 + quad * 8];
            sacc[nt] = __builtin_amdgcn_mfma_f32_16x16x32_bf16(aq[s], bk, sacc[nt], 0, 0, 0);
        }

    // --- online softmax in exp2 domain: s' = s * 0.125 * log2(e) ---
    const float SCL = 0.18033688011112042f;   // 0.125 * 1.4426950408889634
    float p[4][4];
    #pragma unroll
    for (int r = 0; r < 4; r++) {
        float mv = -INFINITY;
        #pragma unroll
        for (int nt = 0; nt < 4; nt++) {
            float s = sacc[nt][r] * SCL;
            if (DIAG && (nt * 16 + col) > (qrow0 + r)) s = -INFINITY;
            p[nt][r] = s;
            mv = fmaxf(mv, s);
        }
        #pragma unroll
        for (int off = 1; off < 16; off <<= 1)
            mv = fmaxf(mv, __shfl_xor(mv, off));
        float mnew = fmaxf(m_i[r], mv);
        float alpha = __builtin_amdgcn_exp2f(m_i[r] - mnew);
        float rsum = 0.f;
        #pragma unroll
        for (int nt = 0; nt < 4; nt++) {
            float e = __builtin_amdgcn_exp2f(p[nt][r] - mnew);
            p[nt][r] = e;
            rsum += e;
        }
        #pragma unroll
        for (int off = 1; off < 16; off <<= 1)
            rsum += __shfl_xor(rsum, off);
        l_i[r] = l_i[r] * alpha + rsum;
        m_i[r] = mnew;
        #pragma unroll
        for (int nt = 0; nt < 4; nt++) acc_o[nt][r] *= alpha;
    }

    // --- P: C/D layout -> A layout via wave-private LDS (no block barrier) ---
    #pragma unroll
    for (int r = 0; r < 4; r++)
        #pragma unroll
        for (int nt = 0; nt < 4; nt++)
            pw[(quad * 4 + r) * LDK + nt * 16 + col] = f2bf(p[nt][r]);
    __builtin_amdgcn_wave_barrier();   // ordering only; lgkmcnt handles the wait

    short8 ap[2];
    ap[0] = *(const short8*)&pw[col * LDK + quad * 8];
    ap[1] = *(const short8*)&pw[col * LDK + 32 + quad * 8];

    // --- O += P V ---
    #pragma unroll
    for (int s = 0; s < 2; s++)
        #pragma unroll
        for (int nt = 0; nt < 4; nt++) {
            short8 bv = *(const short8*)&Vsh[(nt * 16 + col) * LDK + s * 32 + quad * 8];
            acc_o[nt] = __builtin_amdgcn_mfma_f32_16x16x32_bf16(ap[s], bv, acc_o[nt], 0, 0, 0);
        }
}

__global__ __launch_bounds__(256) void attn_kernel(
    const short* __restrict__ Qg, const short* __restrict__ Kg,
    const short* __restrict__ Vg, short* __restrict__ Y)
{
    __shared__ __align__(16) short Ksh[64 * LDK];
    __shared__ __align__(16) short Vsh[64 * LDK];      // [dim][key]
    __shared__ __align__(16) short Psh[4][16 * LDK];   // per-wave P strip

    const int tid  = threadIdx.x;
    const int wave = tid >> 6;
    const int lane = tid & 63;
    const int col  = lane & 15;
    const int quad = lane >> 4;
    const int bh = blockIdx.x;               // 0..95
    const int qt = 15 - blockIdx.y;          // heavy-first dispatch
    const int b = bh / NH, h = bh - b * NH;

    const size_t kqbase = (size_t)bh * SEQ * HD;   // q,k: [bh][t][d]
    const size_t vbase  = (size_t)bh * HD * SEQ;   // v:   [bh][d][t]

    short8 aq[2];
    {
        const short* qp = Qg + kqbase + (size_t)(qt * 64 + wave * 16 + col) * HD + quad * 8;
        aq[0] = *(const short8*)(qp);
        aq[1] = *(const short8*)(qp + 32);
    }

    floatx4 acc_o[4];
    #pragma unroll
    for (int i = 0; i < 4; i++) acc_o[i] = (floatx4){0.f, 0.f, 0.f, 0.f};
    float m_i[4], l_i[4];
    #pragma unroll
    for (int r = 0; r < 4; r++) { m_i[r] = -INFINITY; l_i[r] = 0.f; }

    const int qrow0 = wave * 16 + quad * 4;

    // staging offsets: each thread moves 2 x 16B per operand
    const int idx0 = tid * 8, idx1 = (256 + tid) * 8;
    const int row0 = idx0 >> 6, offs0 = idx0 & 63;
    const int row1 = idx1 >> 6, offs1 = idx1 & 63;

    short8 kreg[2], vreg[2];
    {   // preload tile 0
        const short* ksrc = Kg + kqbase;
        const short* vsrc = Vg + vbase;
        kreg[0] = *(const short8*)&ksrc[idx0];
        kreg[1] = *(const short8*)&ksrc[idx1];
        vreg[0] = *(const short8*)&vsrc[(size_t)row0 * SEQ + offs0];
        vreg[1] = *(const short8*)&vsrc[(size_t)row1 * SEQ + offs1];
    }

    short* pw = Psh[wave];
    for (int kt = 0; kt <= qt; kt++) {
        __syncthreads();   // prior tile's readers done
        *(short8*)&Ksh[row0 * LDK + offs0] = kreg[0];
        *(short8*)&Ksh[row1 * LDK + offs1] = kreg[1];
        *(short8*)&Vsh[row0 * LDK + offs0] = vreg[0];
        *(short8*)&Vsh[row1 * LDK + offs1] = vreg[1];
        __syncthreads();

        if (kt < qt) {   // prefetch next tile while computing this one
            const short* ksrc = Kg + kqbase + (size_t)(kt + 1) * 64 * HD;
            const short* vsrc = Vg + vbase + (kt + 1) * 64;
            kreg[0] = *(const short8*)&ksrc[idx0];
            kreg[1] = *(const short8*)&ksrc[idx1];
            vreg[0] = *(const short8*)&vsrc[(size_t)row0 * SEQ + offs0];
            vreg[1] = *(const short8*)&vsrc[(size_t)row1 * SEQ + offs1];
            attn_step<false>(Ksh, Vsh, pw, aq, acc_o, m_i, l_i, col, quad, qrow0);
        } else {
            attn_step<true>(Ksh, Vsh, pw, aq, acc_o, m_i, l_i, col, quad, qrow0);
        }
    }

    // epilogue: normalize, write y[B,T,C] bf16 (feeds GEMM2 directly)
    #pragma unroll
    for (int r = 0; r < 4; r++) {
        float inv = 1.f / l_i[r];
        int t = qt * 64 + qrow0 + r;
        size_t ybase = ((size_t)(b * SEQ + t)) * CH + h * HD;
        #pragma unroll
        for (int nt = 0; nt < 4; nt++)
            Y[ybase + nt * 16 + col] = f2bf(acc_o[nt][r] * inv);
    }
}

// ---------------------------------------------------------------------------
extern "C" void kernel_launch(void* const* d_in, const int* in_sizes, int n_in,
                              void* d_out, int out_size, void* d_ws, size_t ws_size,
                              hipStream_t stream)
{
    const float* x      = (const float*)d_in[0];  // [B,T,C]
    const float* w_attn = (const float*)d_in[1];  // [C,3C]
    const float* b_attn = (const float*)d_in[2];  // [3C]
    const float* w_proj = (const float*)d_in[3];  // [C,C]
    const float* b_proj = (const float*)d_in[4];  // [C]
    float* out = (float*)d_out;                   // [B,T,C] fp32

    // workspace layout (bf16 shorts)
    short* qkv16 = (short*)d_ws;                          // 3*HSZ
    short* y16   = qkv16 + (size_t)3 * HSZ;               // HSZ   [B,T,C]
    short* xb    = y16   + (size_t)HSZ;                   // HSZ   [B*T, C]
    short* wta   = xb    + (size_t)HSZ;                   // [3C, C] = w_attn^T
    short* wtp   = wta   + (size_t)3 * CH * CH;           // [C, C]  = w_proj^T

    const int M = BATCH * SEQ;   // 8192

    // Fused prep: cast x + transpose-cast both weights (one launch)
    prep_kernel<<<NCAST + NTA + NTP, 256, 0, stream>>>(x, xb, w_attn, wta, w_proj, wtp);

    // GEMM1: qkv = x @ w_attn + b_attn -> bf16 q/k/v (v transposed)
    dim3 g1(3 * CH / 128, M / 128);    // (18, 64)
    gemm_bt_kernel<1><<<g1, 256, 0, stream>>>(xb, wta, b_attn, qkv16, M, 3 * CH, CH);

    // Flash attention -> y16 bf16 [B,T,C]; heavy q-tiles dispatch first
    dim3 ga(BATCH * NH, SEQ / 64);     // (96, 16)
    attn_kernel<<<ga, 256, 0, stream>>>(qkv16, qkv16 + (size_t)HSZ,
                                        qkv16 + (size_t)2 * HSZ, y16);

    // GEMM2: out = y @ w_proj + b_proj (fp32 out)
    dim3 g2(CH / 128, M / 128);        // (6, 64)
    gemm_bt_kernel<0><<<g2, 256, 0, stream>>>(y16, wtp, b_proj, out, M, CH, CH);
}

// Round 5
// 224.818 us; speedup vs baseline: 7.6783x; 1.0176x over previous
//
#include <hip/hip_runtime.h>
#include <hip/hip_bf16.h>
#include <math.h>

// Problem constants (B=8, T=1024, C=768, H=12, D=64)
#define BATCH 8
#define SEQ   1024
#define CH    768
#define NH    12
#define HD    64
#define HSZ   (BATCH * NH * SEQ * HD)   // 6291456 elements = B*T*C

typedef __attribute__((ext_vector_type(8))) short short8;   // 8 bf16 = 4 VGPRs
typedef __attribute__((ext_vector_type(4))) short short4v;
typedef __attribute__((ext_vector_type(4))) float floatx4;  // MFMA C/D frag

// fp32 -> bf16 RNE
static __device__ inline short f2bf(float f) {
    union { float f; unsigned u; } x; x.f = f;
    unsigned r = (x.u + 0x7fffu + ((x.u >> 16) & 1u)) >> 16;
    return (short)r;
}

// ---------------------------------------------------------------------------
// Fused prep (one launch): cast x fp32->bf16; transpose-cast w_attn and w_proj
// to bf16 [N,K]. Block role decoded from blockIdx.x.
// ---------------------------------------------------------------------------
#define NCAST (BATCH * SEQ * CH / 1024)          // 6144 blocks, 1024 elems each
#define NTA   ((3 * CH / 32) * (CH / 32))        // 1728 tiles for w_attn
#define NTP   ((CH / 32) * (CH / 32))            // 576 tiles for w_proj

__device__ __forceinline__ void transpose_tile(
    const float* __restrict__ w, short* __restrict__ wt, int K, int N,
    int bx, int by, int tid, float (*tile)[33])
{
    const int tx = tid & 31, ty = tid >> 5;      // 32 x 8
    const int n0 = bx * 32, k0 = by * 32;
    #pragma unroll
    for (int i = 0; i < 4; i++)
        tile[ty + i * 8][tx] = w[(size_t)(k0 + ty + i * 8) * N + n0 + tx];
    __syncthreads();
    #pragma unroll
    for (int i = 0; i < 4; i++)
        wt[(size_t)(n0 + ty + i * 8) * K + k0 + tx] = f2bf(tile[tx][ty + i * 8]);
}

__global__ __launch_bounds__(256) void prep_kernel(
    const float* __restrict__ x, short* __restrict__ xb,
    const float* __restrict__ wa, short* __restrict__ wta,
    const float* __restrict__ wp, short* __restrict__ wtp)
{
    __shared__ float tile[32][33];
    const int bid = blockIdx.x, tid = threadIdx.x;
    if (bid < NCAST) {
        int i = (bid * 256 + tid) * 4;
        float4 v = *(const float4*)(x + i);
        short4v o = { f2bf(v.x), f2bf(v.y), f2bf(v.z), f2bf(v.w) };
        *(short4v*)(xb + i) = o;
    } else if (bid < NCAST + NTA) {
        int t = bid - NCAST;
        transpose_tile(wa, wta, CH, 3 * CH, t % (3 * CH / 32), t / (3 * CH / 32), tid, tile);
    } else {
        int t = bid - NCAST - NTA;
        transpose_tile(wp, wtp, CH, CH, t % (CH / 32), t / (CH / 32), tid, tile);
    }
}

// ---------------------------------------------------------------------------
// bf16 MFMA GEMM, register-prefetch pipelined:  C[M,N] = A[M,K] @ Bt[N,K]^T + b
// BMx128 tile, BK=32, 256 threads = 4 waves in 2x2; wave tile (BM/2)x64 via
// MT x 4 grid of mfma_f32_16x16x32_bf16.
// Pipeline: global loads for tile k+1 issue right after the barrier and retire
// one full compute phase later (ds_write at next iteration top) — no vmcnt(0)
// drain at the barrier.
// MODE 0: fp32 row-major store; MODE 1: bf16 scatter to q/k/v (v transposed).
// BM=128 for GEMM1 (1152 blocks); BM=64 for GEMM2 (768 blocks, was 384).
// ---------------------------------------------------------------------------
template <int MODE, int BM>
__global__ __launch_bounds__(256) void gemm_bt_kernel(
    const short* __restrict__ A, const short* __restrict__ Bt,
    const float* __restrict__ bias, void* __restrict__ outv,
    int M, int N, int K)
{
    constexpr int MT = BM / 32;                    // wave m-tiles (4 or 2)
    __shared__ __align__(16) short As[BM * 32];
    __shared__ __align__(16) short Bs[128 * 32];

    const int tid  = threadIdx.x;
    const int lane = tid & 63;
    const int col  = lane & 15;
    const int quad = lane >> 4;
    const int wave = tid >> 6;
    const int wm = wave & 1, wn = wave >> 1;
    const int m0 = blockIdx.y * BM, n0 = blockIdx.x * 128;

    // staging: rows are 64 B (32 bf16); each thread owns 16-B chunks
    const int off0 = tid * 16;                     // 0..4080
    const int off1 = 4096 + tid * 16;              // 4096..8176
    const int r0 = off0 >> 6, i0 = (off0 & 63) >> 1;
    const int r1 = off1 >> 6, i1 = (off1 & 63) >> 1;
    const short* agp0 = A  + (size_t)(m0 + r0) * K + i0;
    const short* agp1 = A  + (size_t)(m0 + r1) * K + i1;   // BM==128 only
    const short* bgp0 = Bt + (size_t)(n0 + r0) * K + i0;
    const short* bgp1 = Bt + (size_t)(n0 + r1) * K + i1;

    floatx4 acc[MT][4];
    #pragma unroll
    for (int i = 0; i < MT; i++)
        #pragma unroll
        for (int j = 0; j < 4; j++)
            acc[i][j] = (floatx4){0.f, 0.f, 0.f, 0.f};

    // prologue: tile 0 into registers
    short8 ar0, ar1, br0, br1;
    ar0 = *(const short8*)agp0;
    if (BM == 128) ar1 = *(const short8*)agp1;
    br0 = *(const short8*)bgp0;
    br1 = *(const short8*)bgp1;

    for (int k0 = 0; k0 < K; k0 += 32) {
        __syncthreads();                 // prior tile's readers done
        *(short8*)&As[off0 >> 1] = ar0;
        if (BM == 128) *(short8*)&As[off1 >> 1] = ar1;
        *(short8*)&Bs[off0 >> 1] = br0;
        *(short8*)&Bs[off1 >> 1] = br1;
        __syncthreads();                 // writes visible (lgkm drain only)

        if (k0 + 32 < K) {               // prefetch next tile under the MFMAs
            ar0 = *(const short8*)(agp0 + k0 + 32);
            if (BM == 128) ar1 = *(const short8*)(agp1 + k0 + 32);
            br0 = *(const short8*)(bgp0 + k0 + 32);
            br1 = *(const short8*)(bgp1 + k0 + 32);
        }

        short8 af[MT], bf[4];
        #pragma unroll
        for (int mt = 0; mt < MT; mt++)
            af[mt] = *(short8*)&As[(wm * (BM / 2) + mt * 16 + col) * 32 + quad * 8];
        #pragma unroll
        for (int nt = 0; nt < 4; nt++)
            bf[nt] = *(short8*)&Bs[(wn * 64 + nt * 16 + col) * 32 + quad * 8];
        #pragma unroll
        for (int mt = 0; mt < MT; mt++)
            #pragma unroll
            for (int nt = 0; nt < 4; nt++)
                acc[mt][nt] = __builtin_amdgcn_mfma_f32_16x16x32_bf16(
                    af[mt], bf[nt], acc[mt][nt], 0, 0, 0);
    }

    // Epilogue. C/D layout: row = quad*4 + r, col = col.
    #pragma unroll
    for (int mt = 0; mt < MT; mt++) {
        #pragma unroll
        for (int r = 0; r < 4; r++) {
            const int m = m0 + wm * (BM / 2) + mt * 16 + quad * 4 + r;
            const int bb = m >> 10, t = m & 1023;
            #pragma unroll
            for (int nt = 0; nt < 4; nt++) {
                const int n = n0 + wn * 64 + nt * 16 + col;
                const float v = acc[mt][nt][r] + bias[n];
                if (MODE == 0) {
                    ((float*)outv)[(size_t)m * N + n] = v;
                } else {
                    const int sel = n / CH;
                    const int rem = n - sel * CH;
                    const int hh = rem >> 6, d = rem & 63;
                    size_t dst;
                    if (sel == 2)   // v transposed: [B,H,D,T]
                        dst = (size_t)2 * HSZ + (((size_t)(bb * NH + hh)) * HD + d) * SEQ + t;
                    else
                        dst = (size_t)sel * HSZ + (((size_t)(bb * NH + hh)) * SEQ + t) * HD + d;
                    ((short*)outv)[dst] = f2bf(v);
                }
            }
        }
    }
}

// ---------------------------------------------------------------------------
// bf16 MFMA flash attention (unchanged from round 4):
//  - software-pipelined K/V staging, 2 barriers/tile, wave-private P exchange
//  - diagonal tile peeled, exp2-domain softmax, heavy-first dispatch
// ---------------------------------------------------------------------------
#define LDK 72   // padded row length (bf16) -> 144 B stride, 2-way bank alias (free)

template <bool DIAG>
__device__ __forceinline__ void attn_step(
    const short* __restrict__ Ksh, const short* __restrict__ Vsh,
    short* __restrict__ pw, const short8* aq, floatx4* acc_o,
    float* m_i, float* l_i, int col, int quad, int qrow0)
{
    floatx4 sacc[4];
    #pragma unroll
    for (int i = 0; i < 4; i++) sacc[i] = (floatx4){0.f, 0.f, 0.f, 0.f};
    #pragma unroll
    for (int s = 0; s < 2; s++)
        #pragma unroll
        for (int nt = 0; nt < 4; nt++) {
            short8 bk = *(const short8*)&Ksh[(nt * 16 + col) * LDK + s * 32 + quad * 8];
            sacc[nt] = __builtin_amdgcn_mfma_f32_16x16x32_bf16(aq[s], bk, sacc[nt], 0, 0, 0);
        }

    const float SCL = 0.18033688011112042f;   // 0.125 * log2(e)
    float p[4][4];
    #pragma unroll
    for (int r = 0; r < 4; r++) {
        float mv = -INFINITY;
        #pragma unroll
        for (int nt = 0; nt < 4; nt++) {
            float s = sacc[nt][r] * SCL;
            if (DIAG && (nt * 16 + col) > (qrow0 + r)) s = -INFINITY;
            p[nt][r] = s;
            mv = fmaxf(mv, s);
        }
        #pragma unroll
        for (int off = 1; off < 16; off <<= 1)
            mv = fmaxf(mv, __shfl_xor(mv, off));
        float mnew = fmaxf(m_i[r], mv);
        float alpha = __builtin_amdgcn_exp2f(m_i[r] - mnew);
        float rsum = 0.f;
        #pragma unroll
        for (int nt = 0; nt < 4; nt++) {
            float e = __builtin_amdgcn_exp2f(p[nt][r] - mnew);
            p[nt][r] = e;
            rsum += e;
        }
        #pragma unroll
        for (int off = 1; off < 16; off <<= 1)
            rsum += __shfl_xor(rsum, off);
        l_i[r] = l_i[r] * alpha + rsum;
        m_i[r] = mnew;
        #pragma unroll
        for (int nt = 0; nt < 4; nt++) acc_o[nt][r] *= alpha;
    }

    #pragma unroll
    for (int r = 0; r < 4; r++)
        #pragma unroll
        for (int nt = 0; nt < 4; nt++)
            pw[(quad * 4 + r) * LDK + nt * 16 + col] = f2bf(p[nt][r]);
    __builtin_amdgcn_wave_barrier();

    short8 ap[2];
    ap[0] = *(const short8*)&pw[col * LDK + quad * 8];
    ap[1] = *(const short8*)&pw[col * LDK + 32 + quad * 8];

    #pragma unroll
    for (int s = 0; s < 2; s++)
        #pragma unroll
        for (int nt = 0; nt < 4; nt++) {
            short8 bv = *(const short8*)&Vsh[(nt * 16 + col) * LDK + s * 32 + quad * 8];
            acc_o[nt] = __builtin_amdgcn_mfma_f32_16x16x32_bf16(ap[s], bv, acc_o[nt], 0, 0, 0);
        }
}

__global__ __launch_bounds__(256) void attn_kernel(
    const short* __restrict__ Qg, const short* __restrict__ Kg,
    const short* __restrict__ Vg, short* __restrict__ Y)
{
    __shared__ __align__(16) short Ksh[64 * LDK];
    __shared__ __align__(16) short Vsh[64 * LDK];      // [dim][key]
    __shared__ __align__(16) short Psh[4][16 * LDK];   // per-wave P strip

    const int tid  = threadIdx.x;
    const int wave = tid >> 6;
    const int lane = tid & 63;
    const int col  = lane & 15;
    const int quad = lane >> 4;
    const int bh = blockIdx.x;               // 0..95
    const int qt = 15 - blockIdx.y;          // heavy-first dispatch
    const int b = bh / NH, h = bh - b * NH;

    const size_t kqbase = (size_t)bh * SEQ * HD;   // q,k: [bh][t][d]
    const size_t vbase  = (size_t)bh * HD * SEQ;   // v:   [bh][d][t]

    short8 aq[2];
    {
        const short* qp = Qg + kqbase + (size_t)(qt * 64 + wave * 16 + col) * HD + quad * 8;
        aq[0] = *(const short8*)(qp);
        aq[1] = *(const short8*)(qp + 32);
    }

    floatx4 acc_o[4];
    #pragma unroll
    for (int i = 0; i < 4; i++) acc_o[i] = (floatx4){0.f, 0.f, 0.f, 0.f};
    float m_i[4], l_i[4];
    #pragma unroll
    for (int r = 0; r < 4; r++) { m_i[r] = -INFINITY; l_i[r] = 0.f; }

    const int qrow0 = wave * 16 + quad * 4;

    const int idx0 = tid * 8, idx1 = (256 + tid) * 8;
    const int row0 = idx0 >> 6, offs0 = idx0 & 63;
    const int row1 = idx1 >> 6, offs1 = idx1 & 63;

    short8 kreg[2], vreg[2];
    {
        const short* ksrc = Kg + kqbase;
        const short* vsrc = Vg + vbase;
        kreg[0] = *(const short8*)&ksrc[idx0];
        kreg[1] = *(const short8*)&ksrc[idx1];
        vreg[0] = *(const short8*)&vsrc[(size_t)row0 * SEQ + offs0];
        vreg[1] = *(const short8*)&vsrc[(size_t)row1 * SEQ + offs1];
    }

    short* pw = Psh[wave];
    for (int kt = 0; kt <= qt; kt++) {
        __syncthreads();
        *(short8*)&Ksh[row0 * LDK + offs0] = kreg[0];
        *(short8*)&Ksh[row1 * LDK + offs1] = kreg[1];
        *(short8*)&Vsh[row0 * LDK + offs0] = vreg[0];
        *(short8*)&Vsh[row1 * LDK + offs1] = vreg[1];
        __syncthreads();

        if (kt < qt) {
            const short* ksrc = Kg + kqbase + (size_t)(kt + 1) * 64 * HD;
            const short* vsrc = Vg + vbase + (kt + 1) * 64;
            kreg[0] = *(const short8*)&ksrc[idx0];
            kreg[1] = *(const short8*)&ksrc[idx1];
            vreg[0] = *(const short8*)&vsrc[(size_t)row0 * SEQ + offs0];
            vreg[1] = *(const short8*)&vsrc[(size_t)row1 * SEQ + offs1];
            attn_step<false>(Ksh, Vsh, pw, aq, acc_o, m_i, l_i, col, quad, qrow0);
        } else {
            attn_step<true>(Ksh, Vsh, pw, aq, acc_o, m_i, l_i, col, quad, qrow0);
        }
    }

    #pragma unroll
    for (int r = 0; r < 4; r++) {
        float inv = 1.f / l_i[r];
        int t = qt * 64 + qrow0 + r;
        size_t ybase = ((size_t)(b * SEQ + t)) * CH + h * HD;
        #pragma unroll
        for (int nt = 0; nt < 4; nt++)
            Y[ybase + nt * 16 + col] = f2bf(acc_o[nt][r] * inv);
    }
}

// ---------------------------------------------------------------------------
extern "C" void kernel_launch(void* const* d_in, const int* in_sizes, int n_in,
                              void* d_out, int out_size, void* d_ws, size_t ws_size,
                              hipStream_t stream)
{
    const float* x      = (const float*)d_in[0];  // [B,T,C]
    const float* w_attn = (const float*)d_in[1];  // [C,3C]
    const float* b_attn = (const float*)d_in[2];  // [3C]
    const float* w_proj = (const float*)d_in[3];  // [C,C]
    const float* b_proj = (const float*)d_in[4];  // [C]
    float* out = (float*)d_out;                   // [B,T,C] fp32

    // workspace layout (bf16 shorts)
    short* qkv16 = (short*)d_ws;                          // 3*HSZ
    short* y16   = qkv16 + (size_t)3 * HSZ;               // HSZ   [B,T,C]
    short* xb    = y16   + (size_t)HSZ;                   // HSZ   [B*T, C]
    short* wta   = xb    + (size_t)HSZ;                   // [3C, C] = w_attn^T
    short* wtp   = wta   + (size_t)3 * CH * CH;           // [C, C]  = w_proj^T

    const int M = BATCH * SEQ;   // 8192

    // Fused prep: cast x + transpose-cast both weights (one launch)
    prep_kernel<<<NCAST + NTA + NTP, 256, 0, stream>>>(x, xb, w_attn, wta, w_proj, wtp);

    // GEMM1: qkv = x @ w_attn + b_attn -> bf16 q/k/v (v transposed)
    dim3 g1(3 * CH / 128, M / 128);    // (18, 64)
    gemm_bt_kernel<1, 128><<<g1, 256, 0, stream>>>(xb, wta, b_attn, qkv16, M, 3 * CH, CH);

    // Flash attention -> y16 bf16 [B,T,C]; heavy q-tiles dispatch first
    dim3 ga(BATCH * NH, SEQ / 64);     // (96, 16)
    attn_kernel<<<ga, 256, 0, stream>>>(qkv16, qkv16 + (size_t)HSZ,
                                        qkv16 + (size_t)2 * HSZ, y16);

    // GEMM2: out = y @ w_proj + b_proj (fp32 out), BM=64 for 768 blocks
    dim3 g2(CH / 128, M / 64);         // (6, 128)
    gemm_bt_kernel<0, 64><<<g2, 256, 0, stream>>>(y16, wtp, b_proj, out, M, CH, CH);
}

// Round 6
// 220.147 us; speedup vs baseline: 7.8412x; 1.0212x over previous
//
#include <hip/hip_runtime.h>
#include <hip/hip_bf16.h>
#include <math.h>

// Problem constants (B=8, T=1024, C=768, H=12, D=64)
#define BATCH 8
#define SEQ   1024
#define CH    768
#define NH    12
#define HD    64
#define HSZ   (BATCH * NH * SEQ * HD)   // 6291456 elements = B*T*C

typedef __attribute__((ext_vector_type(8))) short short8;   // 8 bf16 = 4 VGPRs
typedef __attribute__((ext_vector_type(4))) short short4v;
typedef __attribute__((ext_vector_type(4))) float floatx4;  // MFMA C/D frag

// fp32 -> bf16 RNE
static __device__ inline short f2bf(float f) {
    union { float f; unsigned u; } x; x.f = f;
    unsigned r = (x.u + 0x7fffu + ((x.u >> 16) & 1u)) >> 16;
    return (short)r;
}

// ---------------------------------------------------------------------------
// Fused prep (one launch): cast x fp32->bf16; transpose-cast w_attn and w_proj
// to bf16 [N,K]. Block role decoded from blockIdx.x.
// ---------------------------------------------------------------------------
#define NCAST (BATCH * SEQ * CH / 1024)          // 6144 blocks, 1024 elems each
#define NTA   ((3 * CH / 32) * (CH / 32))        // 1728 tiles for w_attn
#define NTP   ((CH / 32) * (CH / 32))            // 576 tiles for w_proj

__device__ __forceinline__ void transpose_tile(
    const float* __restrict__ w, short* __restrict__ wt, int K, int N,
    int bx, int by, int tid, float (*tile)[33])
{
    const int tx = tid & 31, ty = tid >> 5;      // 32 x 8
    const int n0 = bx * 32, k0 = by * 32;
    #pragma unroll
    for (int i = 0; i < 4; i++)
        tile[ty + i * 8][tx] = w[(size_t)(k0 + ty + i * 8) * N + n0 + tx];
    __syncthreads();
    #pragma unroll
    for (int i = 0; i < 4; i++)
        wt[(size_t)(n0 + ty + i * 8) * K + k0 + tx] = f2bf(tile[tx][ty + i * 8]);
}

__global__ __launch_bounds__(256) void prep_kernel(
    const float* __restrict__ x, short* __restrict__ xb,
    const float* __restrict__ wa, short* __restrict__ wta,
    const float* __restrict__ wp, short* __restrict__ wtp)
{
    __shared__ float tile[32][33];
    const int bid = blockIdx.x, tid = threadIdx.x;
    if (bid < NCAST) {
        int i = (bid * 256 + tid) * 4;
        float4 v = *(const float4*)(x + i);
        short4v o = { f2bf(v.x), f2bf(v.y), f2bf(v.z), f2bf(v.w) };
        *(short4v*)(xb + i) = o;
    } else if (bid < NCAST + NTA) {
        int t = bid - NCAST;
        transpose_tile(wa, wta, CH, 3 * CH, t % (3 * CH / 32), t / (3 * CH / 32), tid, tile);
    } else {
        int t = bid - NCAST - NTA;
        transpose_tile(wp, wtp, CH, CH, t % (CH / 32), t / (CH / 32), tid, tile);
    }
}

// ---------------------------------------------------------------------------
// bf16 MFMA GEMM, round-6 structure:  C[M,N] = A[M,K] @ Bt[N,K]^T + bias[N]
//  - double-buffered LDS, ONE barrier per K-tile (writes go to the buffer the
//    MFMAs are NOT reading; no write->read barrier needed)
//  - 2-phase-deep register pipeline: global loads for tile k+3 issue during
//    tile k's compute, ds_written two phases later -> vmcnt wait covers HBM
//  - loop unrolled x2 so stage registers are statically indexed (no scratch)
// BMx128 tile, BK=32, 256 threads = 4 waves in 2x2; wave tile (BM/2)x64 via
// MT x 4 grid of mfma_f32_16x16x32_bf16.
// MODE 0: fp32 row-major store; MODE 1: bf16 scatter to q/k/v (v transposed).
// ---------------------------------------------------------------------------
template <int MODE, int BM>
__global__ __launch_bounds__(256) void gemm_bt_kernel(
    const short* __restrict__ A, const short* __restrict__ Bt,
    const float* __restrict__ bias, void* __restrict__ outv,
    int M, int N, int K)
{
    constexpr int MT = BM / 32;                    // wave m-tiles (4 or 2)
    __shared__ __align__(16) short As[2][BM * 32];
    __shared__ __align__(16) short Bs[2][128 * 32];

    const int tid  = threadIdx.x;
    const int lane = tid & 63;
    const int col  = lane & 15;
    const int quad = lane >> 4;
    const int wave = tid >> 6;
    const int wm = wave & 1, wn = wave >> 1;
    const int m0 = blockIdx.y * BM, n0 = blockIdx.x * 128;

    // staging: rows are 64 B (32 bf16); each thread owns 16-B chunks
    const int off0 = tid * 16;                     // 0..4080
    const int off1 = 4096 + tid * 16;              // 4096..8176
    const int r0 = off0 >> 6, i0 = (off0 & 63) >> 1;
    const int r1 = off1 >> 6, i1 = (off1 & 63) >> 1;
    const short* agp0 = A  + (size_t)(m0 + r0) * K + i0;
    const short* agp1 = A  + (size_t)(m0 + r1) * K + i1;   // BM==128 only
    const short* bgp0 = Bt + (size_t)(n0 + r0) * K + i0;
    const short* bgp1 = Bt + (size_t)(n0 + r1) * K + i1;

    floatx4 acc[MT][4];
    #pragma unroll
    for (int i = 0; i < MT; i++)
        #pragma unroll
        for (int j = 0; j < 4; j++)
            acc[i][j] = (floatx4){0.f, 0.f, 0.f, 0.f};

    // two register stages (statically indexed)
    short8 Aa0, Aa1, Ba0, Ba1;   // stage a
    short8 Ab0, Ab1, Bb0, Bb1;   // stage b

    auto gload = [&](int t, short8& x0, short8& x1, short8& y0, short8& y1) {
        const int ko = t * 32;
        x0 = *(const short8*)(agp0 + ko);
        if (BM == 128) x1 = *(const short8*)(agp1 + ko);
        y0 = *(const short8*)(bgp0 + ko);
        y1 = *(const short8*)(bgp1 + ko);
    };
    auto swrite = [&](short* dA, short* dB, const short8& x0, const short8& x1,
                      const short8& y0, const short8& y1) {
        *(short8*)&dA[off0 >> 1] = x0;
        if (BM == 128) *(short8*)&dA[off1 >> 1] = x1;
        *(short8*)&dB[off0 >> 1] = y0;
        *(short8*)&dB[off1 >> 1] = y1;
    };
    auto compute = [&](const short* sA, const short* sB) {
        short8 af[MT], bf[4];
        #pragma unroll
        for (int mt = 0; mt < MT; mt++)
            af[mt] = *(const short8*)&sA[(wm * (BM / 2) + mt * 16 + col) * 32 + quad * 8];
        #pragma unroll
        for (int nt = 0; nt < 4; nt++)
            bf[nt] = *(const short8*)&sB[(wn * 64 + nt * 16 + col) * 32 + quad * 8];
        #pragma unroll
        for (int mt = 0; mt < MT; mt++)
            #pragma unroll
            for (int nt = 0; nt < 4; nt++)
                acc[mt][nt] = __builtin_amdgcn_mfma_f32_16x16x32_bf16(
                    af[mt], bf[nt], acc[mt][nt], 0, 0, 0);
    };

    const int nt = K / 32;   // 24 (even)

    // prologue: buf0 <- t0; stage b <- t1; stage a <- t2
    gload(0, Aa0, Aa1, Ba0, Ba1);
    gload(1, Ab0, Ab1, Bb0, Bb1);
    swrite(As[0], Bs[0], Aa0, Aa1, Ba0, Ba1);
    gload(2, Aa0, Aa1, Ba0, Ba1);
    __syncthreads();

    for (int k = 0; k < nt; k += 2) {
        // even: compute t_k from buf0; write t_{k+1} (stage b) to buf1; load t_{k+3}
        swrite(As[1], Bs[1], Ab0, Ab1, Bb0, Bb1);
        if (k + 3 < nt) gload(k + 3, Ab0, Ab1, Bb0, Bb1);
        compute(As[0], Bs[0]);
        __syncthreads();
        // odd: compute t_{k+1} from buf1; write t_{k+2} (stage a) to buf0; load t_{k+4}
        if (k + 2 < nt) swrite(As[0], Bs[0], Aa0, Aa1, Ba0, Ba1);
        if (k + 4 < nt) gload(k + 4, Aa0, Aa1, Ba0, Ba1);
        compute(As[1], Bs[1]);
        __syncthreads();
    }

    // Epilogue. C/D layout: row = quad*4 + r, col = col.
    #pragma unroll
    for (int mt = 0; mt < MT; mt++) {
        #pragma unroll
        for (int r = 0; r < 4; r++) {
            const int m = m0 + wm * (BM / 2) + mt * 16 + quad * 4 + r;
            const int bb = m >> 10, t = m & 1023;
            #pragma unroll
            for (int nt4 = 0; nt4 < 4; nt4++) {
                const int n = n0 + wn * 64 + nt4 * 16 + col;
                const float v = acc[mt][nt4][r] + bias[n];
                if (MODE == 0) {
                    ((float*)outv)[(size_t)m * N + n] = v;
                } else {
                    const int sel = n / CH;
                    const int rem = n - sel * CH;
                    const int hh = rem >> 6, d = rem & 63;
                    size_t dst;
                    if (sel == 2)   // v transposed: [B,H,D,T]
                        dst = (size_t)2 * HSZ + (((size_t)(bb * NH + hh)) * HD + d) * SEQ + t;
                    else
                        dst = (size_t)sel * HSZ + (((size_t)(bb * NH + hh)) * SEQ + t) * HD + d;
                    ((short*)outv)[dst] = f2bf(v);
                }
            }
        }
    }
}

// ---------------------------------------------------------------------------
// bf16 MFMA flash attention (unchanged from round 5):
//  - software-pipelined K/V staging, 2 barriers/tile, wave-private P exchange
//  - diagonal tile peeled, exp2-domain softmax, heavy-first dispatch
// ---------------------------------------------------------------------------
#define LDK 72   // padded row length (bf16) -> 144 B stride, 2-way bank alias (free)

template <bool DIAG>
__device__ __forceinline__ void attn_step(
    const short* __restrict__ Ksh, const short* __restrict__ Vsh,
    short* __restrict__ pw, const short8* aq, floatx4* acc_o,
    float* m_i, float* l_i, int col, int quad, int qrow0)
{
    floatx4 sacc[4];
    #pragma unroll
    for (int i = 0; i < 4; i++) sacc[i] = (floatx4){0.f, 0.f, 0.f, 0.f};
    #pragma unroll
    for (int s = 0; s < 2; s++)
        #pragma unroll
        for (int nt = 0; nt < 4; nt++) {
            short8 bk = *(const short8*)&Ksh[(nt * 16 + col) * LDK + s * 32 + quad * 8];
            sacc[nt] = __builtin_amdgcn_mfma_f32_16x16x32_bf16(aq[s], bk, sacc[nt], 0, 0, 0);
        }

    const float SCL = 0.18033688011112042f;   // 0.125 * log2(e)
    float p[4][4];
    #pragma unroll
    for (int r = 0; r < 4; r++) {
        float mv = -INFINITY;
        #pragma unroll
        for (int nt = 0; nt < 4; nt++) {
            float s = sacc[nt][r] * SCL;
            if (DIAG && (nt * 16 + col) > (qrow0 + r)) s = -INFINITY;
            p[nt][r] = s;
            mv = fmaxf(mv, s);
        }
        #pragma unroll
        for (int off = 1; off < 16; off <<= 1)
            mv = fmaxf(mv, __shfl_xor(mv, off));
        float mnew = fmaxf(m_i[r], mv);
        float alpha = __builtin_amdgcn_exp2f(m_i[r] - mnew);
        float rsum = 0.f;
        #pragma unroll
        for (int nt = 0; nt < 4; nt++) {
            float e = __builtin_amdgcn_exp2f(p[nt][r] - mnew);
            p[nt][r] = e;
            rsum += e;
        }
        #pragma unroll
        for (int off = 1; off < 16; off <<= 1)
            rsum += __shfl_xor(rsum, off);
        l_i[r] = l_i[r] * alpha + rsum;
        m_i[r] = mnew;
        #pragma unroll
        for (int nt = 0; nt < 4; nt++) acc_o[nt][r] *= alpha;
    }

    #pragma unroll
    for (int r = 0; r < 4; r++)
        #pragma unroll
        for (int nt = 0; nt < 4; nt++)
            pw[(quad * 4 + r) * LDK + nt * 16 + col] = f2bf(p[nt][r]);
    __builtin_amdgcn_wave_barrier();

    short8 ap[2];
    ap[0] = *(const short8*)&pw[col * LDK + quad * 8];
    ap[1] = *(const short8*)&pw[col * LDK + 32 + quad * 8];

    #pragma unroll
    for (int s = 0; s < 2; s++)
        #pragma unroll
        for (int nt = 0; nt < 4; nt++) {
            short8 bv = *(const short8*)&Vsh[(nt * 16 + col) * LDK + s * 32 + quad * 8];
            acc_o[nt] = __builtin_amdgcn_mfma_f32_16x16x32_bf16(ap[s], bv, acc_o[nt], 0, 0, 0);
        }
}

__global__ __launch_bounds__(256) void attn_kernel(
    const short* __restrict__ Qg, const short* __restrict__ Kg,
    const short* __restrict__ Vg, short* __restrict__ Y)
{
    __shared__ __align__(16) short Ksh[64 * LDK];
    __shared__ __align__(16) short Vsh[64 * LDK];      // [dim][key]
    __shared__ __align__(16) short Psh[4][16 * LDK];   // per-wave P strip

    const int tid  = threadIdx.x;
    const int wave = tid >> 6;
    const int lane = tid & 63;
    const int col  = lane & 15;
    const int quad = lane >> 4;
    const int bh = blockIdx.x;               // 0..95
    const int qt = 15 - blockIdx.y;          // heavy-first dispatch
    const int b = bh / NH, h = bh - b * NH;

    const size_t kqbase = (size_t)bh * SEQ * HD;   // q,k: [bh][t][d]
    const size_t vbase  = (size_t)bh * HD * SEQ;   // v:   [bh][d][t]

    short8 aq[2];
    {
        const short* qp = Qg + kqbase + (size_t)(qt * 64 + wave * 16 + col) * HD + quad * 8;
        aq[0] = *(const short8*)(qp);
        aq[1] = *(const short8*)(qp + 32);
    }

    floatx4 acc_o[4];
    #pragma unroll
    for (int i = 0; i < 4; i++) acc_o[i] = (floatx4){0.f, 0.f, 0.f, 0.f};
    float m_i[4], l_i[4];
    #pragma unroll
    for (int r = 0; r < 4; r++) { m_i[r] = -INFINITY; l_i[r] = 0.f; }

    const int qrow0 = wave * 16 + quad * 4;

    const int idx0 = tid * 8, idx1 = (256 + tid) * 8;
    const int row0 = idx0 >> 6, offs0 = idx0 & 63;
    const int row1 = idx1 >> 6, offs1 = idx1 & 63;

    short8 kreg[2], vreg[2];
    {
        const short* ksrc = Kg + kqbase;
        const short* vsrc = Vg + vbase;
        kreg[0] = *(const short8*)&ksrc[idx0];
        kreg[1] = *(const short8*)&ksrc[idx1];
        vreg[0] = *(const short8*)&vsrc[(size_t)row0 * SEQ + offs0];
        vreg[1] = *(const short8*)&vsrc[(size_t)row1 * SEQ + offs1];
    }

    short* pw = Psh[wave];
    for (int kt = 0; kt <= qt; kt++) {
        __syncthreads();
        *(short8*)&Ksh[row0 * LDK + offs0] = kreg[0];
        *(short8*)&Ksh[row1 * LDK + offs1] = kreg[1];
        *(short8*)&Vsh[row0 * LDK + offs0] = vreg[0];
        *(short8*)&Vsh[row1 * LDK + offs1] = vreg[1];
        __syncthreads();

        if (kt < qt) {
            const short* ksrc = Kg + kqbase + (size_t)(kt + 1) * 64 * HD;
            const short* vsrc = Vg + vbase + (kt + 1) * 64;
            kreg[0] = *(const short8*)&ksrc[idx0];
            kreg[1] = *(const short8*)&ksrc[idx1];
            vreg[0] = *(const short8*)&vsrc[(size_t)row0 * SEQ + offs0];
            vreg[1] = *(const short8*)&vsrc[(size_t)row1 * SEQ + offs1];
            attn_step<false>(Ksh, Vsh, pw, aq, acc_o, m_i, l_i, col, quad, qrow0);
        } else {
            attn_step<true>(Ksh, Vsh, pw, aq, acc_o, m_i, l_i, col, quad, qrow0);
        }
    }

    #pragma unroll
    for (int r = 0; r < 4; r++) {
        float inv = 1.f / l_i[r];
        int t = qt * 64 + qrow0 + r;
        size_t ybase = ((size_t)(b * SEQ + t)) * CH + h * HD;
        #pragma unroll
        for (int nt = 0; nt < 4; nt++)
            Y[ybase + nt * 16 + col] = f2bf(acc_o[nt][r] * inv);
    }
}

// ---------------------------------------------------------------------------
extern "C" void kernel_launch(void* const* d_in, const int* in_sizes, int n_in,
                              void* d_out, int out_size, void* d_ws, size_t ws_size,
                              hipStream_t stream)
{
    const float* x      = (const float*)d_in[0];  // [B,T,C]
    const float* w_attn = (const float*)d_in[1];  // [C,3C]
    const float* b_attn = (const float*)d_in[2];  // [3C]
    const float* w_proj = (const float*)d_in[3];  // [C,C]
    const float* b_proj = (const float*)d_in[4];  // [C]
    float* out = (float*)d_out;                   // [B,T,C] fp32

    // workspace layout (bf16 shorts)
    short* qkv16 = (short*)d_ws;                          // 3*HSZ
    short* y16   = qkv16 + (size_t)3 * HSZ;               // HSZ   [B,T,C]
    short* xb    = y16   + (size_t)HSZ;                   // HSZ   [B*T, C]
    short* wta   = xb    + (size_t)HSZ;                   // [3C, C] = w_attn^T
    short* wtp   = wta   + (size_t)3 * CH * CH;           // [C, C]  = w_proj^T

    const int M = BATCH * SEQ;   // 8192

    // Fused prep: cast x + transpose-cast both weights (one launch)
    prep_kernel<<<NCAST + NTA + NTP, 256, 0, stream>>>(x, xb, w_attn, wta, w_proj, wtp);

    // GEMM1: qkv = x @ w_attn + b_attn -> bf16 q/k/v (v transposed)
    dim3 g1(3 * CH / 128, M / 128);    // (18, 64)
    gemm_bt_kernel<1, 128><<<g1, 256, 0, stream>>>(xb, wta, b_attn, qkv16, M, 3 * CH, CH);

    // Flash attention -> y16 bf16 [B,T,C]; heavy q-tiles dispatch first
    dim3 ga(BATCH * NH, SEQ / 64);     // (96, 16)
    attn_kernel<<<ga, 256, 0, stream>>>(qkv16, qkv16 + (size_t)HSZ,
                                        qkv16 + (size_t)2 * HSZ, y16);

    // GEMM2: out = y @ w_proj + b_proj (fp32 out), BM=64 for 768 blocks
    dim3 g2(CH / 128, M / 64);         // (6, 128)
    gemm_bt_kernel<0, 64><<<g2, 256, 0, stream>>>(y16, wtp, b_proj, out, M, CH, CH);
}